// Round 14
// baseline (196.714 us; speedup 1.0000x reference)
//
#include <hip/hip_runtime.h>
#include <hip/hip_bf16.h>

#define HH 1024
#define WW 1024
#define CC 8
#define LL 8
#define RAD 25
#define EPSV 1e-6f
#define SEG 16              // rows per vertical prefix segment
#define NSEG (HH / SEG)     // 64
#define NPL 72              // 64 joint planes + 8 oc planes
#define NTASK (NSEG * CC * 9)   // 4608 wave-tasks
#define NBLK  (NTASK / 2)       // 2304 blocks (2 waves each) = 9/CU exact
#define BPX   (NBLK / 8)        // 288 blocks per XCD chunk

typedef unsigned short u16;
typedef unsigned int   u32;
typedef u32   u32x4 __attribute__((ext_vector_type(4)));
typedef float f32x4 __attribute__((ext_vector_type(4)));

__device__ __forceinline__ u16 bf16r(float x) {
    u32 b = __float_as_uint(x);
    b += 0x7FFFu + ((b >> 16) & 1u);     // round-to-nearest-even
    return (u16)(b >> 16);
}

// =====================================================================
// K1: per-row horizontal 51-window sums, one WAVE per (segment, c, plane)
// task; rows in PAIRS for 2x MLP. 2-wave blocks: 2304 blocks = 9/CU
// exact residency (LDS 17.4 KB x 9 = 157 KB), 18 waves/CU, no tail.
// XCD-contiguous task swizzle; NT stores for PH/SegT.
// =====================================================================
__global__ __launch_bounds__(128) void hprefix6(const float* __restrict__ ca,
                                                const float* __restrict__ nn,
                                                u16* __restrict__ PH,
                                                float* __restrict__ SegT) {
    const int t    = threadIdx.x;
    const int lane = t & 63;
    const int w    = t >> 6;               // wave in block 0..1
    const int blk  = blockIdx.x;           // 0..2303
    const int task = ((blk & 7) * BPX + (blk >> 3)) * 2 + w;   // 0..4607
    const int yseg = task / (CC * 9);
    const int rem  = task - yseg * (CC * 9);
    const int c    = rem / 9;
    const int p    = rem - c * 9;          // 0..7 joint, 8 = oc plane

    __shared__ float Pbuf[2][2][1088];     // pad-17: word = e + (e>>4)
    float* __restrict__ lp0 = Pbuf[w][0];
    float* __restrict__ lp1 = Pbuf[w][1];

    const int pl = (p < 8) ? (c * 8 + p) : (64 + c);
    const float* carow = ca + (size_t)c * HH * WW + 16 * lane;
    const float* nnrow = nn + (size_t)(p < 8 ? p : 0) * HH * WW + 16 * lane;
    const int x0 = 16 * lane;
    const int b17 = 17 * lane;

    float run[16];
    #pragma unroll
    for (int i = 0; i < 16; ++i) run[i] = 0.f;

    for (int r = 0; r < SEG; r += 2) {
        const int y0 = yseg * SEG + r;
        float a0[16], a1[16];
        // ---- both rows' loads issued together ----
        #pragma unroll
        for (int k = 0; k < 4; ++k) {
            float4 v0 = *(const float4*)(carow + (size_t)y0 * WW + 4 * k);
            float4 v1 = *(const float4*)(carow + (size_t)(y0 + 1) * WW + 4 * k);
            a0[4*k+0] = v0.x + EPSV; a0[4*k+1] = v0.y + EPSV;
            a0[4*k+2] = v0.z + EPSV; a0[4*k+3] = v0.w + EPSV;
            a1[4*k+0] = v1.x + EPSV; a1[4*k+1] = v1.y + EPSV;
            a1[4*k+2] = v1.z + EPSV; a1[4*k+3] = v1.w + EPSV;
        }
        if (p < 8) {
            #pragma unroll
            for (int k = 0; k < 4; ++k) {
                float4 v0 = *(const float4*)(nnrow + (size_t)y0 * WW + 4 * k);
                float4 v1 = *(const float4*)(nnrow + (size_t)(y0 + 1) * WW + 4 * k);
                a0[4*k+0] *= v0.x; a0[4*k+1] *= v0.y;
                a0[4*k+2] *= v0.z; a0[4*k+3] *= v0.w;
                a1[4*k+0] *= v1.x; a1[4*k+1] *= v1.y;
                a1[4*k+2] *= v1.z; a1[4*k+3] *= v1.w;
            }
        }
        // ---- two independent register prefixes ----
        #pragma unroll
        for (int i = 1; i < 16; ++i) { a0[i] += a0[i-1]; a1[i] += a1[i-1]; }
        // ---- two interleaved wave scans (independent shfl chains) ----
        float tot0 = a0[15], tot1 = a1[15];
        float sc0 = tot0, sc1 = tot1;
        #pragma unroll
        for (int off = 1; off < 64; off <<= 1) {
            float v0 = __shfl_up(sc0, off);
            float v1 = __shfl_up(sc1, off);
            if (lane >= off) { sc0 += v0; sc1 += v1; }
        }
        float base0 = sc0 - tot0, base1 = sc1 - tot1;
        // ---- publish both rows' prefixes ----
        #pragma unroll
        for (int i = 0; i < 16; ++i) {
            lp0[b17 + i] = a0[i] + base0;
            lp1[b17 + i] = a1[i] + base1;
        }
        // ---- window sums for both rows ----
        float W0[16], W1[16];
        #pragma unroll
        for (int i = 0; i < 16; ++i) {
            int eh = x0 + i + RAD; eh = (eh > WW - 1) ? WW - 1 : eh;
            int el = x0 + i - RAD - 1;
            int ehp = eh + (eh >> 4);
            float hi0 = lp0[ehp], hi1 = lp1[ehp];
            float lo0 = 0.f, lo1 = 0.f;
            if (el >= 0) { int elp = el + (el >> 4); lo0 = lp0[elp]; lo1 = lp1[elp]; }
            W0[i] = hi0 - lo0;
            W1[i] = hi1 - lo1;
        }
        // ---- vertical running prefix + stores (row 0 then row 1) ----
        u32 pk[8];
        #pragma unroll
        for (int i = 0; i < 16; ++i) run[i] += W0[i];
        #pragma unroll
        for (int j = 0; j < 8; ++j)
            pk[j] = (u32)bf16r(run[2*j]) | ((u32)bf16r(run[2*j+1]) << 16);
        u16* dst0 = PH + ((size_t)pl * HH + y0) * WW + x0;
        { u32x4 q0; q0.x = pk[0]; q0.y = pk[1]; q0.z = pk[2]; q0.w = pk[3];
          u32x4 q1; q1.x = pk[4]; q1.y = pk[5]; q1.z = pk[6]; q1.w = pk[7];
          __builtin_nontemporal_store(q0, (u32x4*)dst0);
          __builtin_nontemporal_store(q1, (u32x4*)(dst0 + 8)); }
        #pragma unroll
        for (int i = 0; i < 16; ++i) run[i] += W1[i];
        #pragma unroll
        for (int j = 0; j < 8; ++j)
            pk[j] = (u32)bf16r(run[2*j]) | ((u32)bf16r(run[2*j+1]) << 16);
        u16* dst1 = dst0 + WW;
        { u32x4 q0; q0.x = pk[0]; q0.y = pk[1]; q0.z = pk[2]; q0.w = pk[3];
          u32x4 q1; q1.x = pk[4]; q1.y = pk[5]; q1.z = pk[6]; q1.w = pk[7];
          __builtin_nontemporal_store(q0, (u32x4*)dst1);
          __builtin_nontemporal_store(q1, (u32x4*)(dst1 + 8)); }
    }
    // segment totals (f32, exact), non-temporal
    float* st = SegT + ((size_t)pl * NSEG + yseg) * WW + x0;
    #pragma unroll
    for (int k = 0; k < 4; ++k) {
        f32x4 v; v.x = run[4*k+0]; v.y = run[4*k+1];
        v.z = run[4*k+2]; v.w = run[4*k+3];
        __builtin_nontemporal_store(v, (f32x4*)(st + 4 * k));
    }
}

// =====================================================================
// K1b: exclusive scan of segment totals over the 64 segments.
// grid (NPL, 4), 256 threads; thread owns one x.
// =====================================================================
__global__ __launch_bounds__(256) void segscan(const float* __restrict__ SegT,
                                               float* __restrict__ Off) {
    int p = blockIdx.x;
    int x = blockIdx.y * 256 + threadIdx.x;
    const float* s = SegT + (size_t)p * NSEG * WW + x;
    float*       o = Off  + (size_t)p * NSEG * WW + x;
    float acc = 0.f;
    for (int sg = 0; sg < NSEG; ++sg) {
        float v = s[(size_t)sg * WW];
        o[(size_t)sg * WW] = acc;
        acc += v;
    }
}

// =====================================================================
// windowV: vertical 51-window of a plane via prefix difference.
// =====================================================================
struct F4 { float v0, v1, v2, v3; };

__device__ __forceinline__ F4 windowV(const u16* __restrict__ PH,
                                      const float* __restrict__ Off,
                                      int pl, int yhi, int shi, int haslo,
                                      int ylo, int slo, int x0) {
    ushort4 uh = *(const ushort4*)(PH + ((size_t)pl * HH + yhi) * WW + x0);
    float4  oh = *(const float4*)(Off + ((size_t)pl * NSEG + shi) * WW + x0);
    F4 r;
    r.v0 = __uint_as_float((u32)uh.x << 16) + oh.x;
    r.v1 = __uint_as_float((u32)uh.y << 16) + oh.y;
    r.v2 = __uint_as_float((u32)uh.z << 16) + oh.z;
    r.v3 = __uint_as_float((u32)uh.w << 16) + oh.w;
    if (haslo) {
        ushort4 ul = *(const ushort4*)(PH + ((size_t)pl * HH + ylo) * WW + x0);
        float4  ol = *(const float4*)(Off + ((size_t)pl * NSEG + slo) * WW + x0);
        r.v0 -= __uint_as_float((u32)ul.x << 16) + ol.x;
        r.v1 -= __uint_as_float((u32)ul.y << 16) + ol.y;
        r.v2 -= __uint_as_float((u32)ul.z << 16) + ol.z;
        r.v3 -= __uint_as_float((u32)ul.w << 16) + ol.w;
    }
    return r;
}

// =====================================================================
// K1c: weights Wgt[c][y][x] = (ca+EPS) / Vn. grid 1024 blocks,
// XCD-swizzled so consecutive y land on the same XCD (L2 window reuse).
// =====================================================================
__global__ __launch_bounds__(256) void wgtk(const float* __restrict__ ca,
                                            const u16* __restrict__ PH,
                                            const float* __restrict__ Off,
                                            float* __restrict__ Wgt) {
    const int b   = blockIdx.x;            // 0..1023
    const int y   = (b & 7) * 128 + (b >> 3);   // bijective XCD swizzle
    const int t   = threadIdx.x;
    const int x0  = 4 * t;
    const int yhi   = (y + RAD > HH - 1) ? HH - 1 : y + RAD;
    const int shi   = yhi / SEG;
    const int haslo = (y - RAD - 1 >= 0) ? 1 : 0;
    const int ylo   = haslo ? y - RAD - 1 : 0;
    const int slo   = ylo / SEG;

    #pragma unroll
    for (int c = 0; c < CC; ++c) {
        F4 Vn = windowV(PH, Off, 64 + c, yhi, shi, haslo, ylo, slo, x0);
        float4 oc4 = *(const float4*)(ca + ((size_t)c * HH + y) * WW + x0);
        float4 w;
        w.x = (oc4.x + EPSV) / Vn.v0;
        w.y = (oc4.y + EPSV) / Vn.v1;
        w.z = (oc4.z + EPSV) / Vn.v2;
        w.w = (oc4.w + EPSV) / Vn.v3;
        *(float4*)(Wgt + ((size_t)c * HH + y) * WW + x0) = w;
    }
}

// =====================================================================
// K2: out[l,y,x] = sum_c Wgt * V(joint). grid 4096 blocks, XCD-swizzled
// (512 consecutive works per XCD = 128 consecutive y x 4 l-pairs).
// =====================================================================
__global__ __launch_bounds__(256) void vcombine3(const float* __restrict__ Wgt,
                                                 const u16* __restrict__ PH,
                                                 const float* __restrict__ Off,
                                                 float* __restrict__ out) {
    const int b    = blockIdx.x;           // 0..4095
    const int work = (b & 7) * 512 + (b >> 3);  // bijective XCD swizzle
    const int y    = work >> 2;
    const int l0   = (work & 3) << 1;
    const int t  = threadIdx.x;
    const int x0 = 4 * t;
    const int yhi   = (y + RAD > HH - 1) ? HH - 1 : y + RAD;
    const int shi   = yhi / SEG;
    const int haslo = (y - RAD - 1 >= 0) ? 1 : 0;
    const int ylo   = haslo ? y - RAD - 1 : 0;
    const int slo   = ylo / SEG;

    float a00 = 0.f, a01 = 0.f, a02 = 0.f, a03 = 0.f;
    float a10 = 0.f, a11 = 0.f, a12 = 0.f, a13 = 0.f;

    #pragma unroll
    for (int c = 0; c < CC; ++c) {
        float4 w4 = *(const float4*)(Wgt + ((size_t)c * HH + y) * WW + x0);
        F4 Vj0 = windowV(PH, Off, c * LL + l0,     yhi, shi, haslo, ylo, slo, x0);
        F4 Vj1 = windowV(PH, Off, c * LL + l0 + 1, yhi, shi, haslo, ylo, slo, x0);
        a00 += w4.x * Vj0.v0; a01 += w4.y * Vj0.v1;
        a02 += w4.z * Vj0.v2; a03 += w4.w * Vj0.v3;
        a10 += w4.x * Vj1.v0; a11 += w4.y * Vj1.v1;
        a12 += w4.z * Vj1.v2; a13 += w4.w * Vj1.v3;
    }
    float4 o0; o0.x = a00; o0.y = a01; o0.z = a02; o0.w = a03;
    float4 o1; o1.x = a10; o1.y = a11; o1.z = a12; o1.w = a13;
    *(float4*)(out + ((size_t)(l0 + 0) * HH + y) * WW + x0) = o0;
    *(float4*)(out + ((size_t)(l0 + 1) * HH + y) * WW + x0) = o1;
}

// =====================================================================

extern "C" void kernel_launch(void* const* d_in, const int* in_sizes, int n_in,
                              void* d_out, int out_size, void* d_ws, size_t ws_size,
                              hipStream_t stream) {
    const float* ca = (const float*)d_in[0];   // (8,1024,1024)
    const float* nn = (const float*)d_in[1];   // (1,8,1024,1024)
    float* out = (float*)d_out;                // (8,1024,1024)

    // workspace: PH bf16 [72][H][W] (151 MB) | SegT f32 (19 MB)
    //            | Off f32 (19 MB) | Wgt f32 [8][H][W] (33.5 MB) => 222 MB
    u16*   PH   = (u16*)d_ws;
    float* SegT = (float*)((char*)d_ws + (size_t)NPL * HH * WW * sizeof(u16));
    float* Off  = SegT + (size_t)NPL * NSEG * WW;
    float* Wgt  = Off  + (size_t)NPL * NSEG * WW;

    hprefix6<<<dim3(NBLK), 128, 0, stream>>>(ca, nn, PH, SegT);
    segscan<<<dim3(NPL, 4), 256, 0, stream>>>(SegT, Off);
    wgtk<<<dim3(HH), 256, 0, stream>>>(ca, PH, Off, Wgt);
    vcombine3<<<dim3(HH * 4), 256, 0, stream>>>(Wgt, PH, Off, out);
}

// Round 15
// 178.032 us; speedup vs baseline: 1.1049x; 1.1049x over previous
//
#include <hip/hip_runtime.h>
#include <hip/hip_bf16.h>

#define HH 1024
#define WW 1024
#define CC 8
#define LL 8
#define RAD 25
#define EPSV 1e-6f
#define SEG 16              // rows per vertical prefix segment
#define NSEG (HH / SEG)     // 64
#define NPL 72              // 64 joint planes + 8 oc planes
#define NTASK (NSEG * CC * 9)   // 4608 wave-tasks
#define NBLK  (NTASK / 2)       // 2304 blocks (2 waves each)
#define BPX   (NBLK / 8)        // 288 blocks per XCD chunk

typedef unsigned short u16;
typedef unsigned int   u32;
typedef u32   u32x4 __attribute__((ext_vector_type(4)));
typedef float f32x4 __attribute__((ext_vector_type(4)));

__device__ __forceinline__ u16 bf16r(float x) {
    u32 b = __float_as_uint(x);
    b += 0x7FFFu + ((b >> 16) & 1u);     // round-to-nearest-even
    return (u16)(b >> 16);
}

// =====================================================================
// K1: per-row horizontal 51-window sums, one WAVE per (segment, c, plane)
// task; rows in PAIRS for 2x MLP. Plain (cached) stores: PH lands in
// L2/L3 so wgtk/vcombine read it warm; XCD-contiguous task swizzle keeps
// input re-reads in L2.
// =====================================================================
__global__ __launch_bounds__(128) void hprefix6(const float* __restrict__ ca,
                                                const float* __restrict__ nn,
                                                u16* __restrict__ PH,
                                                float* __restrict__ SegT) {
    const int t    = threadIdx.x;
    const int lane = t & 63;
    const int w    = t >> 6;               // wave in block 0..1
    const int blk  = blockIdx.x;           // 0..2303
    const int task = ((blk & 7) * BPX + (blk >> 3)) * 2 + w;   // 0..4607
    const int yseg = task / (CC * 9);
    const int rem  = task - yseg * (CC * 9);
    const int c    = rem / 9;
    const int p    = rem - c * 9;          // 0..7 joint, 8 = oc plane

    __shared__ float Pbuf[2][2][1088];     // pad-17: word = e + (e>>4)
    float* __restrict__ lp0 = Pbuf[w][0];
    float* __restrict__ lp1 = Pbuf[w][1];

    const int pl = (p < 8) ? (c * 8 + p) : (64 + c);
    const float* carow = ca + (size_t)c * HH * WW + 16 * lane;
    const float* nnrow = nn + (size_t)(p < 8 ? p : 0) * HH * WW + 16 * lane;
    const int x0 = 16 * lane;
    const int b17 = 17 * lane;

    float run[16];
    #pragma unroll
    for (int i = 0; i < 16; ++i) run[i] = 0.f;

    for (int r = 0; r < SEG; r += 2) {
        const int y0 = yseg * SEG + r;
        float a0[16], a1[16];
        // ---- both rows' loads issued together ----
        #pragma unroll
        for (int k = 0; k < 4; ++k) {
            float4 v0 = *(const float4*)(carow + (size_t)y0 * WW + 4 * k);
            float4 v1 = *(const float4*)(carow + (size_t)(y0 + 1) * WW + 4 * k);
            a0[4*k+0] = v0.x + EPSV; a0[4*k+1] = v0.y + EPSV;
            a0[4*k+2] = v0.z + EPSV; a0[4*k+3] = v0.w + EPSV;
            a1[4*k+0] = v1.x + EPSV; a1[4*k+1] = v1.y + EPSV;
            a1[4*k+2] = v1.z + EPSV; a1[4*k+3] = v1.w + EPSV;
        }
        if (p < 8) {
            #pragma unroll
            for (int k = 0; k < 4; ++k) {
                float4 v0 = *(const float4*)(nnrow + (size_t)y0 * WW + 4 * k);
                float4 v1 = *(const float4*)(nnrow + (size_t)(y0 + 1) * WW + 4 * k);
                a0[4*k+0] *= v0.x; a0[4*k+1] *= v0.y;
                a0[4*k+2] *= v0.z; a0[4*k+3] *= v0.w;
                a1[4*k+0] *= v1.x; a1[4*k+1] *= v1.y;
                a1[4*k+2] *= v1.z; a1[4*k+3] *= v1.w;
            }
        }
        // ---- two independent register prefixes ----
        #pragma unroll
        for (int i = 1; i < 16; ++i) { a0[i] += a0[i-1]; a1[i] += a1[i-1]; }
        // ---- two interleaved wave scans (independent shfl chains) ----
        float tot0 = a0[15], tot1 = a1[15];
        float sc0 = tot0, sc1 = tot1;
        #pragma unroll
        for (int off = 1; off < 64; off <<= 1) {
            float v0 = __shfl_up(sc0, off);
            float v1 = __shfl_up(sc1, off);
            if (lane >= off) { sc0 += v0; sc1 += v1; }
        }
        float base0 = sc0 - tot0, base1 = sc1 - tot1;
        // ---- publish both rows' prefixes ----
        #pragma unroll
        for (int i = 0; i < 16; ++i) {
            lp0[b17 + i] = a0[i] + base0;
            lp1[b17 + i] = a1[i] + base1;
        }
        // ---- window sums for both rows ----
        float W0[16], W1[16];
        #pragma unroll
        for (int i = 0; i < 16; ++i) {
            int eh = x0 + i + RAD; eh = (eh > WW - 1) ? WW - 1 : eh;
            int el = x0 + i - RAD - 1;
            int ehp = eh + (eh >> 4);
            float hi0 = lp0[ehp], hi1 = lp1[ehp];
            float lo0 = 0.f, lo1 = 0.f;
            if (el >= 0) { int elp = el + (el >> 4); lo0 = lp0[elp]; lo1 = lp1[elp]; }
            W0[i] = hi0 - lo0;
            W1[i] = hi1 - lo1;
        }
        // ---- vertical running prefix + stores (row 0 then row 1) ----
        u32 pk[8];
        #pragma unroll
        for (int i = 0; i < 16; ++i) run[i] += W0[i];
        #pragma unroll
        for (int j = 0; j < 8; ++j)
            pk[j] = (u32)bf16r(run[2*j]) | ((u32)bf16r(run[2*j+1]) << 16);
        u16* dst0 = PH + ((size_t)pl * HH + y0) * WW + x0;
        { u32x4 q0; q0.x = pk[0]; q0.y = pk[1]; q0.z = pk[2]; q0.w = pk[3];
          u32x4 q1; q1.x = pk[4]; q1.y = pk[5]; q1.z = pk[6]; q1.w = pk[7];
          *(u32x4*)dst0       = q0;
          *(u32x4*)(dst0 + 8) = q1; }
        #pragma unroll
        for (int i = 0; i < 16; ++i) run[i] += W1[i];
        #pragma unroll
        for (int j = 0; j < 8; ++j)
            pk[j] = (u32)bf16r(run[2*j]) | ((u32)bf16r(run[2*j+1]) << 16);
        u16* dst1 = dst0 + WW;
        { u32x4 q0; q0.x = pk[0]; q0.y = pk[1]; q0.z = pk[2]; q0.w = pk[3];
          u32x4 q1; q1.x = pk[4]; q1.y = pk[5]; q1.z = pk[6]; q1.w = pk[7];
          *(u32x4*)dst1       = q0;
          *(u32x4*)(dst1 + 8) = q1; }
    }
    // segment totals (f32, exact)
    float* st = SegT + ((size_t)pl * NSEG + yseg) * WW + x0;
    #pragma unroll
    for (int k = 0; k < 4; ++k) {
        f32x4 v; v.x = run[4*k+0]; v.y = run[4*k+1];
        v.z = run[4*k+2]; v.w = run[4*k+3];
        *(f32x4*)(st + 4 * k) = v;
    }
}

// =====================================================================
// K1b: exclusive scan of segment totals over the 64 segments.
// grid (NPL, 4), 256 threads; thread owns one x.
// =====================================================================
__global__ __launch_bounds__(256) void segscan(const float* __restrict__ SegT,
                                               float* __restrict__ Off) {
    int p = blockIdx.x;
    int x = blockIdx.y * 256 + threadIdx.x;
    const float* s = SegT + (size_t)p * NSEG * WW + x;
    float*       o = Off  + (size_t)p * NSEG * WW + x;
    float acc = 0.f;
    for (int sg = 0; sg < NSEG; ++sg) {
        float v = s[(size_t)sg * WW];
        o[(size_t)sg * WW] = acc;
        acc += v;
    }
}

// =====================================================================
// windowV: vertical 51-window of a plane via prefix difference.
// =====================================================================
struct F4 { float v0, v1, v2, v3; };

__device__ __forceinline__ F4 windowV(const u16* __restrict__ PH,
                                      const float* __restrict__ Off,
                                      int pl, int yhi, int shi, int haslo,
                                      int ylo, int slo, int x0) {
    ushort4 uh = *(const ushort4*)(PH + ((size_t)pl * HH + yhi) * WW + x0);
    float4  oh = *(const float4*)(Off + ((size_t)pl * NSEG + shi) * WW + x0);
    F4 r;
    r.v0 = __uint_as_float((u32)uh.x << 16) + oh.x;
    r.v1 = __uint_as_float((u32)uh.y << 16) + oh.y;
    r.v2 = __uint_as_float((u32)uh.z << 16) + oh.z;
    r.v3 = __uint_as_float((u32)uh.w << 16) + oh.w;
    if (haslo) {
        ushort4 ul = *(const ushort4*)(PH + ((size_t)pl * HH + ylo) * WW + x0);
        float4  ol = *(const float4*)(Off + ((size_t)pl * NSEG + slo) * WW + x0);
        r.v0 -= __uint_as_float((u32)ul.x << 16) + ol.x;
        r.v1 -= __uint_as_float((u32)ul.y << 16) + ol.y;
        r.v2 -= __uint_as_float((u32)ul.z << 16) + ol.z;
        r.v3 -= __uint_as_float((u32)ul.w << 16) + ol.w;
    }
    return r;
}

// =====================================================================
// K1c: weights Wgt[c][y][x] = (ca+EPS) / Vn. grid 1024 blocks,
// XCD-swizzled so consecutive y land on the same XCD (L2 window reuse).
// =====================================================================
__global__ __launch_bounds__(256) void wgtk(const float* __restrict__ ca,
                                            const u16* __restrict__ PH,
                                            const float* __restrict__ Off,
                                            float* __restrict__ Wgt) {
    const int b   = blockIdx.x;            // 0..1023
    const int y   = (b & 7) * 128 + (b >> 3);   // bijective XCD swizzle
    const int t   = threadIdx.x;
    const int x0  = 4 * t;
    const int yhi   = (y + RAD > HH - 1) ? HH - 1 : y + RAD;
    const int shi   = yhi / SEG;
    const int haslo = (y - RAD - 1 >= 0) ? 1 : 0;
    const int ylo   = haslo ? y - RAD - 1 : 0;
    const int slo   = ylo / SEG;

    #pragma unroll
    for (int c = 0; c < CC; ++c) {
        F4 Vn = windowV(PH, Off, 64 + c, yhi, shi, haslo, ylo, slo, x0);
        float4 oc4 = *(const float4*)(ca + ((size_t)c * HH + y) * WW + x0);
        float4 w;
        w.x = (oc4.x + EPSV) / Vn.v0;
        w.y = (oc4.y + EPSV) / Vn.v1;
        w.z = (oc4.z + EPSV) / Vn.v2;
        w.w = (oc4.w + EPSV) / Vn.v3;
        *(float4*)(Wgt + ((size_t)c * HH + y) * WW + x0) = w;
    }
}

// =====================================================================
// K2: out[l,y,x] = sum_c Wgt * V(joint). grid 4096 blocks, XCD-swizzled
// (512 consecutive works per XCD = 128 consecutive y x 4 l-pairs).
// =====================================================================
__global__ __launch_bounds__(256) void vcombine3(const float* __restrict__ Wgt,
                                                 const u16* __restrict__ PH,
                                                 const float* __restrict__ Off,
                                                 float* __restrict__ out) {
    const int b    = blockIdx.x;           // 0..4095
    const int work = (b & 7) * 512 + (b >> 3);  // bijective XCD swizzle
    const int y    = work >> 2;
    const int l0   = (work & 3) << 1;
    const int t  = threadIdx.x;
    const int x0 = 4 * t;
    const int yhi   = (y + RAD > HH - 1) ? HH - 1 : y + RAD;
    const int shi   = yhi / SEG;
    const int haslo = (y - RAD - 1 >= 0) ? 1 : 0;
    const int ylo   = haslo ? y - RAD - 1 : 0;
    const int slo   = ylo / SEG;

    float a00 = 0.f, a01 = 0.f, a02 = 0.f, a03 = 0.f;
    float a10 = 0.f, a11 = 0.f, a12 = 0.f, a13 = 0.f;

    #pragma unroll
    for (int c = 0; c < CC; ++c) {
        float4 w4 = *(const float4*)(Wgt + ((size_t)c * HH + y) * WW + x0);
        F4 Vj0 = windowV(PH, Off, c * LL + l0,     yhi, shi, haslo, ylo, slo, x0);
        F4 Vj1 = windowV(PH, Off, c * LL + l0 + 1, yhi, shi, haslo, ylo, slo, x0);
        a00 += w4.x * Vj0.v0; a01 += w4.y * Vj0.v1;
        a02 += w4.z * Vj0.v2; a03 += w4.w * Vj0.v3;
        a10 += w4.x * Vj1.v0; a11 += w4.y * Vj1.v1;
        a12 += w4.z * Vj1.v2; a13 += w4.w * Vj1.v3;
    }
    float4 o0; o0.x = a00; o0.y = a01; o0.z = a02; o0.w = a03;
    float4 o1; o1.x = a10; o1.y = a11; o1.z = a12; o1.w = a13;
    *(float4*)(out + ((size_t)(l0 + 0) * HH + y) * WW + x0) = o0;
    *(float4*)(out + ((size_t)(l0 + 1) * HH + y) * WW + x0) = o1;
}

// =====================================================================

extern "C" void kernel_launch(void* const* d_in, const int* in_sizes, int n_in,
                              void* d_out, int out_size, void* d_ws, size_t ws_size,
                              hipStream_t stream) {
    const float* ca = (const float*)d_in[0];   // (8,1024,1024)
    const float* nn = (const float*)d_in[1];   // (1,8,1024,1024)
    float* out = (float*)d_out;                // (8,1024,1024)

    // workspace: PH bf16 [72][H][W] (151 MB) | SegT f32 (19 MB)
    //            | Off f32 (19 MB) | Wgt f32 [8][H][W] (33.5 MB) => 222 MB
    u16*   PH   = (u16*)d_ws;
    float* SegT = (float*)((char*)d_ws + (size_t)NPL * HH * WW * sizeof(u16));
    float* Off  = SegT + (size_t)NPL * NSEG * WW;
    float* Wgt  = Off  + (size_t)NPL * NSEG * WW;

    hprefix6<<<dim3(NBLK), 128, 0, stream>>>(ca, nn, PH, SegT);
    segscan<<<dim3(NPL, 4), 256, 0, stream>>>(SegT, Off);
    wgtk<<<dim3(HH), 256, 0, stream>>>(ca, PH, Off, Wgt);
    vcombine3<<<dim3(HH * 4), 256, 0, stream>>>(Wgt, PH, Off, out);
}

// Round 17
// 175.986 us; speedup vs baseline: 1.1178x; 1.0116x over previous
//
#include <hip/hip_runtime.h>
#include <hip/hip_bf16.h>

#define HH 1024
#define WW 1024
#define CC 8
#define LL 8
#define RAD 25
#define EPSV 1e-6f
#define SEG 16              // rows per vertical prefix segment
#define NSEG (HH / SEG)     // 64
#define NPL 72              // 64 joint planes + 8 oc planes
#define NTASK (NSEG * CC * 9)   // 4608 wave-tasks
#define NBLK  (NTASK / 2)       // 2304 blocks (2 waves each)
#define BPX   (NBLK / 8)        // 288 blocks per XCD chunk

typedef unsigned short u16;
typedef unsigned int   u32;
typedef u32   u32x4 __attribute__((ext_vector_type(4)));
typedef float f32x4 __attribute__((ext_vector_type(4)));

__device__ __forceinline__ u16 bf16r(float x) {
    u32 b = __float_as_uint(x);
    b += 0x7FFFu + ((b >> 16) & 1u);     // round-to-nearest-even
    return (u16)(b >> 16);
}

// =====================================================================
// K1: per-row horizontal 51-window sums, one WAVE per (segment, c, plane)
// task; rows in PAIRS. LDS layout: [32 zeros][1024 abs prefix][32 total].
// All LDS traffic is b128. The window reads fetch OTHER lanes' writes:
// per-thread the ranges don't alias, so without a barrier the compiler
// may legally hoist ds_read above ds_write (R15 inf bug). __syncthreads
// at each write->read boundary enforces ordering; flow is block-uniform.
// =====================================================================
__global__ __launch_bounds__(128) void hprefix7(const float* __restrict__ ca,
                                                const float* __restrict__ nn,
                                                u16* __restrict__ PH,
                                                float* __restrict__ SegT) {
    const int t    = threadIdx.x;
    const int lane = t & 63;
    const int w    = t >> 6;               // wave in block 0..1
    const int blk  = blockIdx.x;           // 0..2303
    const int task = ((blk & 7) * BPX + (blk >> 3)) * 2 + w;   // 0..4607
    const int yseg = task / (CC * 9);
    const int rem  = task - yseg * (CC * 9);
    const int c    = rem / 9;
    const int p    = rem - c * 9;          // 0..7 joint, 8 = oc plane

    __shared__ __align__(16) float Pbuf[2][2][1088];
    float* __restrict__ lp0 = Pbuf[w][0];
    float* __restrict__ lp1 = Pbuf[w][1];

    const int pl = (p < 8) ? (c * 8 + p) : (64 + c);
    const float* carow = ca + (size_t)c * HH * WW + 16 * lane;
    const float* nnrow = nn + (size_t)(p < 8 ? p : 0) * HH * WW + 16 * lane;
    const int x0 = 16 * lane;

    // zero head (positions -32..-1), written once; rows never touch it
    if (lane < 32) { lp0[lane] = 0.f; lp1[lane] = 0.f; }
    __syncthreads();

    float run[16];
    #pragma unroll
    for (int i = 0; i < 16; ++i) run[i] = 0.f;

    for (int r = 0; r < SEG; r += 2) {
        const int y0 = yseg * SEG + r;
        float a0[16], a1[16];
        // ---- both rows' loads issued together ----
        #pragma unroll
        for (int k = 0; k < 4; ++k) {
            float4 v0 = *(const float4*)(carow + (size_t)y0 * WW + 4 * k);
            float4 v1 = *(const float4*)(carow + (size_t)(y0 + 1) * WW + 4 * k);
            a0[4*k+0] = v0.x + EPSV; a0[4*k+1] = v0.y + EPSV;
            a0[4*k+2] = v0.z + EPSV; a0[4*k+3] = v0.w + EPSV;
            a1[4*k+0] = v1.x + EPSV; a1[4*k+1] = v1.y + EPSV;
            a1[4*k+2] = v1.z + EPSV; a1[4*k+3] = v1.w + EPSV;
        }
        if (p < 8) {
            #pragma unroll
            for (int k = 0; k < 4; ++k) {
                float4 v0 = *(const float4*)(nnrow + (size_t)y0 * WW + 4 * k);
                float4 v1 = *(const float4*)(nnrow + (size_t)(y0 + 1) * WW + 4 * k);
                a0[4*k+0] *= v0.x; a0[4*k+1] *= v0.y;
                a0[4*k+2] *= v0.z; a0[4*k+3] *= v0.w;
                a1[4*k+0] *= v1.x; a1[4*k+1] *= v1.y;
                a1[4*k+2] *= v1.z; a1[4*k+3] *= v1.w;
            }
        }
        // ---- two independent register prefixes ----
        #pragma unroll
        for (int i = 1; i < 16; ++i) { a0[i] += a0[i-1]; a1[i] += a1[i-1]; }
        // ---- two interleaved wave scans ----
        float tot0 = a0[15], tot1 = a1[15];
        float sc0 = tot0, sc1 = tot1;
        #pragma unroll
        for (int off = 1; off < 64; off <<= 1) {
            float v0 = __shfl_up(sc0, off);
            float v1 = __shfl_up(sc1, off);
            if (lane >= off) { sc0 += v0; sc1 += v1; }
        }
        float base0 = sc0 - tot0, base1 = sc1 - tot1;
        float total0 = __shfl(sc0, 63);    // row sum = P[1023]
        float total1 = __shfl(sc1, 63);
        // ---- publish absolute prefixes: 4x ds_write_b128 per row ----
        #pragma unroll
        for (int k = 0; k < 4; ++k) {
            f32x4 v0, v1;
            v0.x = a0[4*k+0] + base0; v0.y = a0[4*k+1] + base0;
            v0.z = a0[4*k+2] + base0; v0.w = a0[4*k+3] + base0;
            v1.x = a1[4*k+0] + base1; v1.y = a1[4*k+1] + base1;
            v1.z = a1[4*k+2] + base1; v1.w = a1[4*k+3] + base1;
            *(f32x4*)&lp0[32 + x0 + 4*k] = v0;
            *(f32x4*)&lp1[32 + x0 + 4*k] = v1;
        }
        // tail pad (positions 1024..1055) = total, for lanes 62/63 clamp
        if (lane < 32) { lp0[1056 + lane] = total0; lp1[1056 + lane] = total1; }
        __syncthreads();                   // writes visible before cross-lane reads

        // ---- row 0: window sums via 5+5 b128 reads + static extraction ----
        u32 pk[8];
        {
            f32x4 Hr[5], Lr[5];
            #pragma unroll
            for (int k = 0; k < 5; ++k) {
                Hr[k] = *(const f32x4*)&lp0[32 + x0 + 24 + 4*k];
                Lr[k] = *(const f32x4*)&lp0[32 + x0 - 28 + 4*k];
            }
            #pragma unroll
            for (int i = 0; i < 16; ++i) {
                float hi = Hr[(i+1) >> 2][(i+1) & 3];   // P[x0+i+25] (or total)
                float lo = Lr[(i+2) >> 2][(i+2) & 3];   // P[x0+i-26] (or 0)
                run[i] += hi - lo;
            }
            #pragma unroll
            for (int j = 0; j < 8; ++j)
                pk[j] = (u32)bf16r(run[2*j]) | ((u32)bf16r(run[2*j+1]) << 16);
            u16* dst0 = PH + ((size_t)pl * HH + y0) * WW + x0;
            u32x4 q0; q0.x = pk[0]; q0.y = pk[1]; q0.z = pk[2]; q0.w = pk[3];
            u32x4 q1; q1.x = pk[4]; q1.y = pk[5]; q1.z = pk[6]; q1.w = pk[7];
            *(u32x4*)dst0       = q0;
            *(u32x4*)(dst0 + 8) = q1;
        }
        // ---- row 1 ----
        {
            f32x4 Hr[5], Lr[5];
            #pragma unroll
            for (int k = 0; k < 5; ++k) {
                Hr[k] = *(const f32x4*)&lp1[32 + x0 + 24 + 4*k];
                Lr[k] = *(const f32x4*)&lp1[32 + x0 - 28 + 4*k];
            }
            #pragma unroll
            for (int i = 0; i < 16; ++i) {
                float hi = Hr[(i+1) >> 2][(i+1) & 3];
                float lo = Lr[(i+2) >> 2][(i+2) & 3];
                run[i] += hi - lo;
            }
            #pragma unroll
            for (int j = 0; j < 8; ++j)
                pk[j] = (u32)bf16r(run[2*j]) | ((u32)bf16r(run[2*j+1]) << 16);
            u16* dst1 = PH + ((size_t)pl * HH + y0 + 1) * WW + x0;
            u32x4 q0; q0.x = pk[0]; q0.y = pk[1]; q0.z = pk[2]; q0.w = pk[3];
            u32x4 q1; q1.x = pk[4]; q1.y = pk[5]; q1.z = pk[6]; q1.w = pk[7];
            *(u32x4*)dst1       = q0;
            *(u32x4*)(dst1 + 8) = q1;
        }
        __syncthreads();                   // reads done before next-iter writes
    }
    // segment totals (f32, exact)
    float* st = SegT + ((size_t)pl * NSEG + yseg) * WW + x0;
    #pragma unroll
    for (int k = 0; k < 4; ++k) {
        f32x4 v; v.x = run[4*k+0]; v.y = run[4*k+1];
        v.z = run[4*k+2]; v.w = run[4*k+3];
        *(f32x4*)(st + 4 * k) = v;
    }
}

// =====================================================================
// K1b: exclusive scan of segment totals over the 64 segments.
// =====================================================================
__global__ __launch_bounds__(256) void segscan(const float* __restrict__ SegT,
                                               float* __restrict__ Off) {
    int p = blockIdx.x;
    int x = blockIdx.y * 256 + threadIdx.x;
    const float* s = SegT + (size_t)p * NSEG * WW + x;
    float*       o = Off  + (size_t)p * NSEG * WW + x;
    float acc = 0.f;
    for (int sg = 0; sg < NSEG; ++sg) {
        float v = s[(size_t)sg * WW];
        o[(size_t)sg * WW] = acc;
        acc += v;
    }
}

// =====================================================================
// windowV: vertical 51-window of a plane via prefix difference.
// =====================================================================
struct F4 { float v0, v1, v2, v3; };

__device__ __forceinline__ F4 windowV(const u16* __restrict__ PH,
                                      const float* __restrict__ Off,
                                      int pl, int yhi, int shi, int haslo,
                                      int ylo, int slo, int x0) {
    ushort4 uh = *(const ushort4*)(PH + ((size_t)pl * HH + yhi) * WW + x0);
    float4  oh = *(const float4*)(Off + ((size_t)pl * NSEG + shi) * WW + x0);
    F4 r;
    r.v0 = __uint_as_float((u32)uh.x << 16) + oh.x;
    r.v1 = __uint_as_float((u32)uh.y << 16) + oh.y;
    r.v2 = __uint_as_float((u32)uh.z << 16) + oh.z;
    r.v3 = __uint_as_float((u32)uh.w << 16) + oh.w;
    if (haslo) {
        ushort4 ul = *(const ushort4*)(PH + ((size_t)pl * HH + ylo) * WW + x0);
        float4  ol = *(const float4*)(Off + ((size_t)pl * NSEG + slo) * WW + x0);
        r.v0 -= __uint_as_float((u32)ul.x << 16) + ol.x;
        r.v1 -= __uint_as_float((u32)ul.y << 16) + ol.y;
        r.v2 -= __uint_as_float((u32)ul.z << 16) + ol.z;
        r.v3 -= __uint_as_float((u32)ul.w << 16) + ol.w;
    }
    return r;
}

// =====================================================================
// K1c: weights Wgt[c][y][x] = (ca+EPS) / Vn.
// =====================================================================
__global__ __launch_bounds__(256) void wgtk(const float* __restrict__ ca,
                                            const u16* __restrict__ PH,
                                            const float* __restrict__ Off,
                                            float* __restrict__ Wgt) {
    const int b   = blockIdx.x;            // 0..1023
    const int y   = (b & 7) * 128 + (b >> 3);   // bijective XCD swizzle
    const int t   = threadIdx.x;
    const int x0  = 4 * t;
    const int yhi   = (y + RAD > HH - 1) ? HH - 1 : y + RAD;
    const int shi   = yhi / SEG;
    const int haslo = (y - RAD - 1 >= 0) ? 1 : 0;
    const int ylo   = haslo ? y - RAD - 1 : 0;
    const int slo   = ylo / SEG;

    #pragma unroll
    for (int c = 0; c < CC; ++c) {
        F4 Vn = windowV(PH, Off, 64 + c, yhi, shi, haslo, ylo, slo, x0);
        float4 oc4 = *(const float4*)(ca + ((size_t)c * HH + y) * WW + x0);
        float4 w;
        w.x = (oc4.x + EPSV) / Vn.v0;
        w.y = (oc4.y + EPSV) / Vn.v1;
        w.z = (oc4.z + EPSV) / Vn.v2;
        w.w = (oc4.w + EPSV) / Vn.v3;
        *(float4*)(Wgt + ((size_t)c * HH + y) * WW + x0) = w;
    }
}

// =====================================================================
// K2: out[l,y,x] = sum_c Wgt * V(joint). grid 4096 blocks, XCD-swizzled.
// =====================================================================
__global__ __launch_bounds__(256) void vcombine3(const float* __restrict__ Wgt,
                                                 const u16* __restrict__ PH,
                                                 const float* __restrict__ Off,
                                                 float* __restrict__ out) {
    const int b    = blockIdx.x;           // 0..4095
    const int work = (b & 7) * 512 + (b >> 3);  // bijective XCD swizzle
    const int y    = work >> 2;
    const int l0   = (work & 3) << 1;
    const int t  = threadIdx.x;
    const int x0 = 4 * t;
    const int yhi   = (y + RAD > HH - 1) ? HH - 1 : y + RAD;
    const int shi   = yhi / SEG;
    const int haslo = (y - RAD - 1 >= 0) ? 1 : 0;
    const int ylo   = haslo ? y - RAD - 1 : 0;
    const int slo   = ylo / SEG;

    float a00 = 0.f, a01 = 0.f, a02 = 0.f, a03 = 0.f;
    float a10 = 0.f, a11 = 0.f, a12 = 0.f, a13 = 0.f;

    #pragma unroll
    for (int c = 0; c < CC; ++c) {
        float4 w4 = *(const float4*)(Wgt + ((size_t)c * HH + y) * WW + x0);
        F4 Vj0 = windowV(PH, Off, c * LL + l0,     yhi, shi, haslo, ylo, slo, x0);
        F4 Vj1 = windowV(PH, Off, c * LL + l0 + 1, yhi, shi, haslo, ylo, slo, x0);
        a00 += w4.x * Vj0.v0; a01 += w4.y * Vj0.v1;
        a02 += w4.z * Vj0.v2; a03 += w4.w * Vj0.v3;
        a10 += w4.x * Vj1.v0; a11 += w4.y * Vj1.v1;
        a12 += w4.z * Vj1.v2; a13 += w4.w * Vj1.v3;
    }
    float4 o0; o0.x = a00; o0.y = a01; o0.z = a02; o0.w = a03;
    float4 o1; o1.x = a10; o1.y = a11; o1.z = a12; o1.w = a13;
    *(float4*)(out + ((size_t)(l0 + 0) * HH + y) * WW + x0) = o0;
    *(float4*)(out + ((size_t)(l0 + 1) * HH + y) * WW + x0) = o1;
}

// =====================================================================

extern "C" void kernel_launch(void* const* d_in, const int* in_sizes, int n_in,
                              void* d_out, int out_size, void* d_ws, size_t ws_size,
                              hipStream_t stream) {
    const float* ca = (const float*)d_in[0];   // (8,1024,1024)
    const float* nn = (const float*)d_in[1];   // (1,8,1024,1024)
    float* out = (float*)d_out;                // (8,1024,1024)

    // workspace: PH bf16 [72][H][W] (151 MB) | SegT f32 (19 MB)
    //            | Off f32 (19 MB) | Wgt f32 [8][H][W] (33.5 MB) => 222 MB
    u16*   PH   = (u16*)d_ws;
    float* SegT = (float*)((char*)d_ws + (size_t)NPL * HH * WW * sizeof(u16));
    float* Off  = SegT + (size_t)NPL * NSEG * WW;
    float* Wgt  = Off  + (size_t)NPL * NSEG * WW;

    hprefix7<<<dim3(NBLK), 128, 0, stream>>>(ca, nn, PH, SegT);
    segscan<<<dim3(NPL, 4), 256, 0, stream>>>(SegT, Off);
    wgtk<<<dim3(HH), 256, 0, stream>>>(ca, PH, Off, Wgt);
    vcombine3<<<dim3(HH * 4), 256, 0, stream>>>(Wgt, PH, Off, out);
}